// Round 1
// baseline (2920.537 us; speedup 1.0000x reference)
//
#include <hip/hip_runtime.h>

// ---------------------------------------------------------------------------
// Recurrent attention scan, one wave per 16 (b) rows of one head h.
//   B=512 T=512 C=64 H=128.  Grid = H * (B/64) = 1024 wgs x 256 thr (4 waves).
// Per step t (per wave, rows = wid*16..wid*16+15):
//   v  = [x_t | att] . [Win|Watt]^T   (16 MFMA 16x16x32 bf16, K=128)
//   y  = tanh(v)            (C/D layout -> LDS -> A layout)
//   e  = y . We^T           (8 MFMA, K=64)
//   att= softmax_c(e);  out[b,t,h] = att . x_t   (quad-group shfl reductions)
// Weight fragments live in registers across the whole T loop (no LDS reads).
// All LDS regions are wave-private (16-row blocks) -> only one barrier/step.
// ---------------------------------------------------------------------------

constexpr int Bsz = 512, Tsz = 512, Csz = 64, Hsz = 128;

typedef __attribute__((ext_vector_type(8))) short short8;
typedef __attribute__((ext_vector_type(4))) float f32x4;

#define APITCH 136  // bf16 elems per A-tile row: [64 rows][0..63 x | 64..127 att] (+pad, 16B aligned)
#define YPITCH 72   // bf16 elems per Y-tile row: [64 rows][64 k] (+pad)

__device__ __forceinline__ unsigned short f2bf(float f) {
    unsigned int u = __float_as_uint(f);
    u += 0x7FFFu + ((u >> 16) & 1u);        // round-to-nearest-even
    return (unsigned short)(u >> 16);
}
__device__ __forceinline__ float bf2f(unsigned short s) {
    return __uint_as_float(((unsigned int)s) << 16);
}

__global__ __launch_bounds__(256, 2)
void attn_scan(const float* __restrict__ xg,
               const float* __restrict__ w_att,
               const float* __restrict__ w_in,
               const float* __restrict__ w_e,
               float* __restrict__ outg)
{
    __shared__ unsigned short Atile[64 * APITCH];
    __shared__ unsigned short Ytile[64 * YPITCH];

    const int h  = blockIdx.x & (Hsz - 1);
    const int b0 = (blockIdx.x >> 7) << 6;       // btile * 64

    const int tid  = threadIdx.x;
    const int wid  = tid >> 6;
    const int lane = tid & 63;
    const int l15  = lane & 15;
    const int quad = lane >> 4;

    // ---- weights -> register fragments (bf16), held across whole T loop ----
    // B-operand frag for D = A.W^T: lane holds W[c = nt*16+l15][k = ks*32+quad*8+j]
    short8 wcat[4][4];   // K=128: ks 0,1 -> Win[h][c][k], ks 2,3 -> Watt[h][c][k-64]
    short8 wef [4][2];   // K=64 : We[h][c][k]
    {
        const float* winh = w_in  + (size_t)h * Csz * Csz;
        const float* wath = w_att + (size_t)h * Csz * Csz;
        const float* weh  = w_e   + (size_t)h * Csz * Csz;
#pragma unroll
        for (int nt = 0; nt < 4; ++nt) {
            const int c = nt * 16 + l15;
#pragma unroll
            for (int ks = 0; ks < 4; ++ks) {
                const int kk = ks * 32 + quad * 8;
                const float* src = (ks < 2) ? (winh + c * 64 + kk)
                                            : (wath + c * 64 + (kk - 64));
                short8 f;
#pragma unroll
                for (int j = 0; j < 8; ++j) f[j] = (short)f2bf(src[j]);
                wcat[nt][ks] = f;
            }
#pragma unroll
            for (int ks = 0; ks < 2; ++ks) {
                const int kk = ks * 32 + quad * 8;
                const float* src = weh + c * 64 + kk;
                short8 f;
#pragma unroll
                for (int j = 0; j < 8; ++j) f[j] = (short)f2bf(src[j]);
                wef[nt][ks] = f;
            }
        }
    }

    // ---- init A-tile: x_0 and att0 = 1/64 (exact bf16 0x3C80) ----
    const int srow = tid >> 2;              // staging row 0..63 (wave-private block)
    const int sc0  = (tid & 3) * 16;        // staging col base
    {
        const float* xp = xg + ((size_t)(b0 + srow) * Tsz) * Csz + sc0;
#pragma unroll
        for (int i = 0; i < 16; ++i) {
            Atile[srow * APITCH + sc0 + i]      = f2bf(xp[i]);
            Atile[srow * APITCH + 64 + sc0 + i] = 0x3C80;
        }
    }
    __syncthreads();

    const int mrow = wid * 16 + l15;        // A-operand frag row
    const int rowb = wid * 16 + quad * 4;   // C/D row base for this lane

    for (int t = 0; t < Tsz; ++t) {
        // -- prefetch x_{t+1} (consumed at loop bottom; hides behind compute) --
        const int tn = (t < Tsz - 1) ? t + 1 : t;
        const float4* xp4 = (const float4*)(xg + ((size_t)(b0 + srow) * Tsz + tn) * Csz + sc0);
        float4 px0 = xp4[0], px1 = xp4[1], px2 = xp4[2], px3 = xp4[3];

        // -- phase A: v = [x|att] . Wcat^T  (K = 128) --
        f32x4 acc[4];
#pragma unroll
        for (int nt = 0; nt < 4; ++nt) acc[nt] = (f32x4){0.f, 0.f, 0.f, 0.f};
#pragma unroll
        for (int ks = 0; ks < 4; ++ks) {
            short8 af = *(const short8*)&Atile[mrow * APITCH + ks * 32 + quad * 8];
#pragma unroll
            for (int nt = 0; nt < 4; ++nt)
                acc[nt] = __builtin_amdgcn_mfma_f32_16x16x32_bf16(af, wcat[nt][ks], acc[nt], 0, 0, 0);
        }

        // -- tanh, C/D layout -> Y-tile (A layout source for phase B) --
#pragma unroll
        for (int nt = 0; nt < 4; ++nt)
#pragma unroll
            for (int rg = 0; rg < 4; ++rg) {
                float v  = acc[nt][rg];
                float ex = __expf(2.0f * v);
                float y  = 1.0f - 2.0f * __builtin_amdgcn_rcpf(ex + 1.0f);
                Ytile[(rowb + rg) * YPITCH + nt * 16 + l15] = f2bf(y);
            }

        // -- phase B: e = y . We^T  (K = 64) --
        f32x4 ecc[4];
#pragma unroll
        for (int nt = 0; nt < 4; ++nt) ecc[nt] = (f32x4){0.f, 0.f, 0.f, 0.f};
#pragma unroll
        for (int ks = 0; ks < 2; ++ks) {
            short8 yf = *(const short8*)&Ytile[mrow * YPITCH + ks * 32 + quad * 8];
#pragma unroll
            for (int nt = 0; nt < 4; ++nt)
                ecc[nt] = __builtin_amdgcn_mfma_f32_16x16x32_bf16(yf, wef[nt][ks], ecc[nt], 0, 0, 0);
        }

        // -- softmax over c (row = quad-group of 16 lanes x 4 nt-regs) + out dot --
        float mx[4];
#pragma unroll
        for (int rg = 0; rg < 4; ++rg)
            mx[rg] = fmaxf(fmaxf(ecc[0][rg], ecc[1][rg]), fmaxf(ecc[2][rg], ecc[3][rg]));
#pragma unroll
        for (int off = 1; off < 16; off <<= 1)
#pragma unroll
            for (int rg = 0; rg < 4; ++rg)
                mx[rg] = fmaxf(mx[rg], __shfl_xor(mx[rg], off));

        float ssum[4] = {0.f, 0.f, 0.f, 0.f};
        float dsum[4] = {0.f, 0.f, 0.f, 0.f};
        float pt[4][4];
#pragma unroll
        for (int nt = 0; nt < 4; ++nt)
#pragma unroll
            for (int rg = 0; rg < 4; ++rg) {
                float p = __expf(ecc[nt][rg] - mx[rg]);
                pt[nt][rg] = p;
                ssum[rg] += p;
                float xv = bf2f(Atile[(rowb + rg) * APITCH + nt * 16 + l15]);
                dsum[rg] += p * xv;
            }
#pragma unroll
        for (int off = 1; off < 16; off <<= 1)
#pragma unroll
            for (int rg = 0; rg < 4; ++rg) {
                ssum[rg] += __shfl_xor(ssum[rg], off);
                dsum[rg] += __shfl_xor(dsum[rg], off);
            }

        float rinv[4], oval[4];
#pragma unroll
        for (int rg = 0; rg < 4; ++rg) {
            rinv[rg] = __builtin_amdgcn_rcpf(ssum[rg]);
            oval[rg] = dsum[rg] * rinv[rg];
        }

        // -- att_{t+1} (normalized, bf16) back into A-tile cols 64..127 --
#pragma unroll
        for (int nt = 0; nt < 4; ++nt)
#pragma unroll
            for (int rg = 0; rg < 4; ++rg)
                Atile[(rowb + rg) * APITCH + 64 + nt * 16 + l15] = f2bf(pt[nt][rg] * rinv[rg]);

        // -- out[b, t, h]: lane quad*16+rg stores row quad*4+rg --
        if (l15 < 4) {
            float v = oval[0];
            v = (l15 == 1) ? oval[1] : v;
            v = (l15 == 2) ? oval[2] : v;
            v = (l15 == 3) ? oval[3] : v;
            outg[(size_t)(b0 + rowb + l15) * (Tsz * Hsz) + (size_t)t * Hsz + h] = v;
        }

        // -- stage x_{t+1} into A-tile cols 0..63 (wave-private rows) --
        {
            short8 lo, hi;
            lo[0] = (short)f2bf(px0.x); lo[1] = (short)f2bf(px0.y);
            lo[2] = (short)f2bf(px0.z); lo[3] = (short)f2bf(px0.w);
            lo[4] = (short)f2bf(px1.x); lo[5] = (short)f2bf(px1.y);
            lo[6] = (short)f2bf(px1.z); lo[7] = (short)f2bf(px1.w);
            hi[0] = (short)f2bf(px2.x); hi[1] = (short)f2bf(px2.y);
            hi[2] = (short)f2bf(px2.z); hi[3] = (short)f2bf(px2.w);
            hi[4] = (short)f2bf(px3.x); hi[5] = (short)f2bf(px3.y);
            hi[6] = (short)f2bf(px3.z); hi[7] = (short)f2bf(px3.w);
            *(short8*)&Atile[srow * APITCH + sc0]     = lo;
            *(short8*)&Atile[srow * APITCH + sc0 + 8] = hi;
        }
        __syncthreads();   // belt-and-braces; waves are row-private so mostly free
    }
}

extern "C" void kernel_launch(void* const* d_in, const int* in_sizes, int n_in,
                              void* d_out, int out_size, void* d_ws, size_t ws_size,
                              hipStream_t stream) {
    // setup_inputs order: x, weight_att, weight_input, weight_e
    const float* x     = (const float*)d_in[0];
    const float* w_att = (const float*)d_in[1];
    const float* w_in  = (const float*)d_in[2];
    const float* w_e   = (const float*)d_in[3];
    float* out = (float*)d_out;

    dim3 grid(Hsz * (Bsz / 64));   // 1024 workgroups: (h, 64-row b-tile)
    dim3 block(256);               // 4 waves; each owns 16 rows end-to-end
    attn_scan<<<grid, block, 0, stream>>>(x, w_att, w_in, w_e, out);
}

// Round 2
// 1863.854 us; speedup vs baseline: 1.5669x; 1.5669x over previous
//
#include <hip/hip_runtime.h>

// ---------------------------------------------------------------------------
// Recurrent attention scan. B=512 T=512 C=64 H=128.
// One WAVE (= one 64-thread workgroup) per (head h, 16 b-rows): grid = 4096.
// All LDS is wave-private -> NO barriers anywhere in the scan kernel.
// Weight fragments (Win|Watt concat, We) live in registers for the whole T
// loop (~96 VGPRs). x is pre-converted to bf16 once (kernel x_to_bf16).
// Softmax: no max subtraction (|e| <= 64*0.05 = 3.2 strictly); reductions
// via full-rate VALU DPP butterflies (no LDS-pipe shuffles).
// Output write-combined: 16 timesteps buffered in LDS -> coalesced float4
// flush to ws[H][B][T] -> transpose kernel -> out[B][T][H].
// ---------------------------------------------------------------------------

constexpr int Bsz = 512, Tsz = 512, Csz = 64, Hsz = 128;

typedef __attribute__((ext_vector_type(8))) short short8;
typedef __attribute__((ext_vector_type(4))) float f32x4;
typedef __attribute__((ext_vector_type(4))) unsigned short us4;

#define APITCH 136  // u16/row: [16 rows][cols 0..63 = x_t | 64..127 = att] + pad
#define YPITCH 72   // u16/row: [16 rows][64] tanh output (A-layout for phase B)
#define OPITCH 20   // f32/row: [16 rows][16 t + pad] out write-combine buffer

__device__ __forceinline__ unsigned short f2bf_rn(float f) {
    return (unsigned short)((__float_as_uint(f) + 0x8000u) >> 16);  // RN (ties away)
}
__device__ __forceinline__ float bf2f(unsigned short s) {
    return __uint_as_float(((unsigned int)s) << 16);
}

template<int CTRL>
__device__ __forceinline__ float dpp_add(float v) {
    int t = __builtin_amdgcn_update_dpp(0, __float_as_int(v), CTRL, 0xF, 0xF, true);
    return v + __int_as_float(t);
}
// sum across each 16-lane row group, result in all 16 lanes (pure VALU)
__device__ __forceinline__ float row_sum16(float v) {
    v = dpp_add<0x128>(v);  // row_ror:8
    v = dpp_add<0x124>(v);  // row_ror:4
    v = dpp_add<0x4E>(v);   // quad_perm [2,3,0,1] = xor 2
    v = dpp_add<0xB1>(v);   // quad_perm [1,0,3,2] = xor 1
    return v;
}

__global__ __launch_bounds__(256, 4)
void x_to_bf16(const float* __restrict__ x, unsigned short* __restrict__ xb, int n4) {
    int i = blockIdx.x * 256 + threadIdx.x;
    if (i < n4) {
        float4 v = ((const float4*)x)[i];
        us4 r;
        r[0] = f2bf_rn(v.x); r[1] = f2bf_rn(v.y);
        r[2] = f2bf_rn(v.z); r[3] = f2bf_rn(v.w);
        ((us4*)xb)[i] = r;
    }
}

template<bool XPRE, bool OUTWS>
__global__ __launch_bounds__(64, 4)
void attn_scan(const float* __restrict__ xg,
               const unsigned short* __restrict__ xbg,
               const float* __restrict__ w_att,
               const float* __restrict__ w_in,
               const float* __restrict__ w_e,
               float* __restrict__ outg,
               float* __restrict__ outws)
{
    __shared__ unsigned short Atile[16 * APITCH];
    __shared__ unsigned short Ytile[16 * YPITCH];
    __shared__ float         OutBuf[16 * OPITCH];

    const int h  = blockIdx.x & (Hsz - 1);
    const int b0 = (blockIdx.x >> 7) << 4;       // 16-row b tile

    const int lane = threadIdx.x;                // 0..63 (one wave)
    const int l15  = lane & 15;
    const int quad = lane >> 4;
    const int rowb = quad * 4;                   // C/D row base
    const int sr   = lane >> 2;                  // staging row 0..15
    const int sc0  = (lane & 3) * 16;            // staging col base

    // ---- weights -> register fragments (bf16), held across the whole T loop
    // B-frag for D = A.W^T: lane holds W[c = nt*16+l15][k = ks*32+quad*8+j]
    short8 wcat[4][4];   // K=128: ks 0,1 -> Win ; ks 2,3 -> Watt
    short8 wef [4][2];   // K=64 : We
    {
        const float* winh = w_in  + (size_t)h * Csz * Csz;
        const float* wath = w_att + (size_t)h * Csz * Csz;
        const float* weh  = w_e   + (size_t)h * Csz * Csz;
#pragma unroll
        for (int nt = 0; nt < 4; ++nt) {
            const int c = nt * 16 + l15;
#pragma unroll
            for (int ks = 0; ks < 4; ++ks) {
                const int kk = ks * 32 + quad * 8;
                const float* src = (ks < 2) ? (winh + c * 64 + kk)
                                            : (wath + c * 64 + (kk - 64));
                short8 f;
#pragma unroll
                for (int j = 0; j < 8; ++j) f[j] = (short)f2bf_rn(src[j]);
                wcat[nt][ks] = f;
            }
#pragma unroll
            for (int ks = 0; ks < 2; ++ks) {
                const float* src = weh + c * 64 + ks * 32 + quad * 8;
                short8 f;
#pragma unroll
                for (int j = 0; j < 8; ++j) f[j] = (short)f2bf_rn(src[j]);
                wef[nt][ks] = f;
            }
        }
    }

    // ---- init A-tile: x_0 and att0 = 1/64 (exact bf16 0x3C80)
    if (XPRE) {
        const unsigned short* xp = xbg + ((size_t)(b0 + sr) * Tsz) * Csz + sc0;
        *(short8*)&Atile[sr * APITCH + sc0]     = *(const short8*)xp;
        *(short8*)&Atile[sr * APITCH + sc0 + 8] = *(const short8*)(xp + 8);
    } else {
        const float* xp = xg + ((size_t)(b0 + sr) * Tsz) * Csz + sc0;
#pragma unroll
        for (int i = 0; i < 16; ++i)
            Atile[sr * APITCH + sc0 + i] = f2bf_rn(xp[i]);
    }
#pragma unroll
    for (int i = 0; i < 16; ++i)
        Atile[sr * APITCH + 64 + sc0 + i] = 0x3C80;

    for (int t = 0; t < Tsz; ++t) {
        // -- prefetch x_{t+1} (consumed at loop bottom) --
        const int tn = (t < Tsz - 1) ? t + 1 : t;
        short8 pxa, pxb;                         // XPRE path
        float4 pf0, pf1, pf2, pf3;               // !XPRE path
        if (XPRE) {
            const unsigned short* xp = xbg + ((size_t)(b0 + sr) * Tsz + tn) * Csz + sc0;
            pxa = *(const short8*)xp;
            pxb = *(const short8*)(xp + 8);
        } else {
            const float4* xp4 = (const float4*)(xg + ((size_t)(b0 + sr) * Tsz + tn) * Csz + sc0);
            pf0 = xp4[0]; pf1 = xp4[1]; pf2 = xp4[2]; pf3 = xp4[3];
        }

        // -- phase A: v = [x|att] . Wcat^T  (K = 128) --
        f32x4 acc[4];
#pragma unroll
        for (int nt = 0; nt < 4; ++nt) acc[nt] = (f32x4){0.f, 0.f, 0.f, 0.f};
#pragma unroll
        for (int ks = 0; ks < 4; ++ks) {
            short8 af = *(const short8*)&Atile[l15 * APITCH + ks * 32 + quad * 8];
#pragma unroll
            for (int nt = 0; nt < 4; ++nt)
                acc[nt] = __builtin_amdgcn_mfma_f32_16x16x32_bf16(af, wcat[nt][ks], acc[nt], 0, 0, 0);
        }

        // -- tanh (C/D layout) -> Y-tile (A-layout source for phase B) --
#pragma unroll
        for (int nt = 0; nt < 4; ++nt)
#pragma unroll
            for (int rg = 0; rg < 4; ++rg) {
                float v  = acc[nt][rg];
                float ex = __expf(2.0f * v);
                float y  = 1.0f - 2.0f * __builtin_amdgcn_rcpf(ex + 1.0f);
                Ytile[(rowb + rg) * YPITCH + nt * 16 + l15] = f2bf_rn(y);
            }

        // -- phase B: e = y . We^T  (K = 64) --
        f32x4 ecc[4];
#pragma unroll
        for (int nt = 0; nt < 4; ++nt) ecc[nt] = (f32x4){0.f, 0.f, 0.f, 0.f};
#pragma unroll
        for (int ks = 0; ks < 2; ++ks) {
            short8 yf = *(const short8*)&Ytile[l15 * YPITCH + ks * 32 + quad * 8];
#pragma unroll
            for (int nt = 0; nt < 4; ++nt)
                ecc[nt] = __builtin_amdgcn_mfma_f32_16x16x32_bf16(yf, wef[nt][ks], ecc[nt], 0, 0, 0);
        }

        // -- softmax (no max: |e| <= 3.2 strictly) + out dot, DPP reductions --
        float pt[4][4], ssum[4], dsum[4];
#pragma unroll
        for (int rg = 0; rg < 4; ++rg) { ssum[rg] = 0.f; dsum[rg] = 0.f; }
#pragma unroll
        for (int nt = 0; nt < 4; ++nt)
#pragma unroll
            for (int rg = 0; rg < 4; ++rg) {
                float p = __expf(ecc[nt][rg]);
                pt[nt][rg] = p;
                ssum[rg] += p;
                float xv = bf2f(Atile[(rowb + rg) * APITCH + nt * 16 + l15]);
                dsum[rg] += p * xv;
            }
        float rinv[4], oval[4];
#pragma unroll
        for (int rg = 0; rg < 4; ++rg) {
            ssum[rg] = row_sum16(ssum[rg]);
            dsum[rg] = row_sum16(dsum[rg]);
            rinv[rg] = __builtin_amdgcn_rcpf(ssum[rg]);
            oval[rg] = dsum[rg] * rinv[rg];
        }

        // -- att_{t+1} (normalized bf16) back into A-tile cols 64..127 --
#pragma unroll
        for (int nt = 0; nt < 4; ++nt)
#pragma unroll
            for (int rg = 0; rg < 4; ++rg)
                Atile[(rowb + rg) * APITCH + 64 + nt * 16 + l15] = f2bf_rn(pt[nt][rg] * rinv[rg]);

        // -- out[b, t, h] --
        if (l15 < 4) {
            float v = oval[0];
            v = (l15 == 1) ? oval[1] : v;
            v = (l15 == 2) ? oval[2] : v;
            v = (l15 == 3) ? oval[3] : v;
            if (OUTWS) {
                OutBuf[(rowb + l15) * OPITCH + (t & 15)] = v;
            } else {
                outg[(size_t)(b0 + rowb + l15) * (Tsz * Hsz) + (size_t)t * Hsz + h] = v;
            }
        }
        if (OUTWS && ((t & 15) == 15)) {
            // flush 16 rows x 16 t, coalesced float4 per lane
            float4 v = *(const float4*)&OutBuf[sr * OPITCH + (lane & 3) * 4];
            *(float4*)&outws[((size_t)h * Bsz + b0 + sr) * Tsz + (t - 15) + (lane & 3) * 4] = v;
        }

        // -- stage x_{t+1} into A-tile cols 0..63 --
        if (XPRE) {
            *(short8*)&Atile[sr * APITCH + sc0]     = pxa;
            *(short8*)&Atile[sr * APITCH + sc0 + 8] = pxb;
        } else {
            short8 lo, hi;
            lo[0] = (short)f2bf_rn(pf0.x); lo[1] = (short)f2bf_rn(pf0.y);
            lo[2] = (short)f2bf_rn(pf0.z); lo[3] = (short)f2bf_rn(pf0.w);
            lo[4] = (short)f2bf_rn(pf1.x); lo[5] = (short)f2bf_rn(pf1.y);
            lo[6] = (short)f2bf_rn(pf1.z); lo[7] = (short)f2bf_rn(pf1.w);
            hi[0] = (short)f2bf_rn(pf2.x); hi[1] = (short)f2bf_rn(pf2.y);
            hi[2] = (short)f2bf_rn(pf2.z); hi[3] = (short)f2bf_rn(pf2.w);
            hi[4] = (short)f2bf_rn(pf3.x); hi[5] = (short)f2bf_rn(pf3.y);
            hi[6] = (short)f2bf_rn(pf3.z); hi[7] = (short)f2bf_rn(pf3.w);
            *(short8*)&Atile[sr * APITCH + sc0]     = lo;
            *(short8*)&Atile[sr * APITCH + sc0 + 8] = hi;
        }
    }
}

// ws[H][B][T] -> out[B][T][H], 64x64 (t,h) tiles per b
__global__ __launch_bounds__(256, 4)
void out_transpose(const float* __restrict__ ws, float* __restrict__ outg) {
    __shared__ float tile[64][65];
    const int t0 = blockIdx.x * 64;
    const int h0 = blockIdx.y * 64;
    const int b  = blockIdx.z;
    const int tx = threadIdx.x & 63;
    const int wy = threadIdx.x >> 6;
#pragma unroll
    for (int i = 0; i < 16; ++i) {
        int hr = wy * 16 + i;
        tile[hr][tx] = ws[((size_t)(h0 + hr) * Bsz + b) * Tsz + t0 + tx];
    }
    __syncthreads();
#pragma unroll
    for (int i = 0; i < 16; ++i) {
        int tt = wy * 16 + i;
        outg[((size_t)b * Tsz + t0 + tt) * Hsz + h0 + tx] = tile[tx][tt];
    }
}

extern "C" void kernel_launch(void* const* d_in, const int* in_sizes, int n_in,
                              void* d_out, int out_size, void* d_ws, size_t ws_size,
                              hipStream_t stream) {
    // setup_inputs order: x, weight_att, weight_input, weight_e
    const float* x     = (const float*)d_in[0];
    const float* w_att = (const float*)d_in[1];
    const float* w_in  = (const float*)d_in[2];
    const float* w_e   = (const float*)d_in[3];
    float* out = (float*)d_out;

    const size_t XB = (size_t)Bsz * Tsz * Csz * sizeof(unsigned short);  // 33.5 MB
    const size_t OB = (size_t)Bsz * Tsz * Hsz * sizeof(float);           // 134 MB
    unsigned short* xb  = (unsigned short*)d_ws;
    float*          ows = (float*)((char*)d_ws + XB);

    const int n4 = Bsz * Tsz * Csz / 4;
    dim3 scan_grid(Hsz * (Bsz / 16));   // 4096 single-wave workgroups

    if (ws_size >= XB + OB) {
        x_to_bf16<<<(n4 + 255) / 256, 256, 0, stream>>>(x, xb, n4);
        attn_scan<true, true><<<scan_grid, 64, 0, stream>>>(x, xb, w_att, w_in, w_e, out, ows);
        dim3 tg(Tsz / 64, Hsz / 64, Bsz);
        out_transpose<<<tg, 256, 0, stream>>>(ows, out);
    } else if (ws_size >= XB) {
        x_to_bf16<<<(n4 + 255) / 256, 256, 0, stream>>>(x, xb, n4);
        attn_scan<true, false><<<scan_grid, 64, 0, stream>>>(x, xb, w_att, w_in, w_e, out, nullptr);
    } else {
        attn_scan<false, false><<<scan_grid, 64, 0, stream>>>(x, nullptr, w_att, w_in, w_e, out, nullptr);
    }
}